// Round 1
// baseline (74.858 us; speedup 1.0000x reference)
//
#include <hip/hip_runtime.h>
#include <math.h>

#define EPS_F 1e-8f

__global__ void __launch_bounds__(256) iou3d_init(double* acc) {
    acc[0] = 0.0;
    acc[1] = 0.0;
}

__global__ void __launch_bounds__(256) iou3d_main(
    const float* __restrict__ pred_iou,
    const float* __restrict__ pred_boxes,   // N x 7: x y z w l h yaw
    const float* __restrict__ gt_boxes,     // N x 8: x y z w l h sin cos
    const int*   __restrict__ mask,
    double* __restrict__ acc,
    int N)
{
    int i = blockIdx.x * blockDim.x + threadIdx.x;
    float wabs = 0.f, mval = 0.f;

    if (i < N) {
        const float* b1 = pred_boxes + (size_t)i * 7;
        const float* b2 = gt_boxes   + (size_t)i * 8;
        float m = (float)mask[i];
        mval = m;

        // 2D box params (idx2d = [0,1,3,4,6])
        float x1c = b1[0], y1c = b1[1], w1 = b1[3], h1 = b1[4], a1 = b1[6];
        float x2c = b2[0], y2c = b2[1], w2 = b2[3], h2 = b2[4];
        float a2 = atan2f(b2[6], b2[7]);

        float c1x[4], c1y[4], c2x[4], c2y[4];
        {
            const float DX[4] = {0.5f, -0.5f, -0.5f, 0.5f};
            const float DY[4] = {0.5f,  0.5f, -0.5f, -0.5f};
            float cs = cosf(a1), sn = sinf(a1);
            #pragma unroll
            for (int k = 0; k < 4; ++k) {
                float cx = DX[k] * w1, cy = DY[k] * h1;
                c1x[k] = cx * cs - cy * sn + x1c;
                c1y[k] = cx * sn + cy * cs + y1c;
            }
            cs = cosf(a2); sn = sinf(a2);
            #pragma unroll
            for (int k = 0; k < 4; ++k) {
                float cx = DX[k] * w2, cy = DY[k] * h2;
                c2x[k] = cx * cs - cy * sn + x2c;
                c2y[k] = cx * sn + cy * cs + y2c;
            }
        }

        float vx[24], vy[24];
        bool  vv[24];

        // corners of box1 inside box2 (indices 0..3), box2 inside box1 (4..7)
        {
            float abx = c2x[1] - c2x[0], aby = c2y[1] - c2y[0];
            float adx = c2x[3] - c2x[0], ady = c2y[3] - c2y[0];
            float ab2 = abx * abx + aby * aby;
            float ad2 = adx * adx + ady * ady;
            #pragma unroll
            for (int k = 0; k < 4; ++k) {
                float amx = c1x[k] - c2x[0], amy = c1y[k] - c2y[0];
                float pab = (abx * amx + aby * amy) / ab2;
                float pad = (adx * amx + ady * amy) / ad2;
                vx[k] = c1x[k]; vy[k] = c1y[k];
                vv[k] = (pab > -1e-6f) && (pab < 1.f + 1e-6f) &&
                        (pad > -1e-6f) && (pad < 1.f + 1e-6f);
            }
            abx = c1x[1] - c1x[0]; aby = c1y[1] - c1y[0];
            adx = c1x[3] - c1x[0]; ady = c1y[3] - c1y[0];
            ab2 = abx * abx + aby * aby;
            ad2 = adx * adx + ady * ady;
            #pragma unroll
            for (int k = 0; k < 4; ++k) {
                float amx = c2x[k] - c1x[0], amy = c2y[k] - c1y[0];
                float pab = (abx * amx + aby * amy) / ab2;
                float pad = (adx * amx + ady * amy) / ad2;
                vx[4 + k] = c2x[k]; vy[4 + k] = c2y[k];
                vv[4 + k] = (pab > -1e-6f) && (pab < 1.f + 1e-6f) &&
                            (pad > -1e-6f) && (pad < 1.f + 1e-6f);
            }
        }

        // 16 edge-edge intersections (indices 8..23, layout 8 + ii*4 + jj)
        #pragma unroll
        for (int ii = 0; ii < 4; ++ii) {
            float ex1 = c1x[ii],        ey1 = c1y[ii];
            float ex2 = c1x[(ii+1)&3],  ey2 = c1y[(ii+1)&3];
            #pragma unroll
            for (int jj = 0; jj < 4; ++jj) {
                float ex3 = c2x[jj],        ey3 = c2y[jj];
                float ex4 = c2x[(jj+1)&3],  ey4 = c2y[(jj+1)&3];
                float num  = (ex2-ex1)*(ey3-ey4) - (ey2-ey1)*(ex3-ex4);
                float dent = (ex1-ex3)*(ey3-ey4) - (ey1-ey3)*(ex3-ex4);
                float t = dent / (num + EPS_F);
                float denu = (ex1-ex3)*(ey1-ey2) - (ey1-ey3)*(ex1-ex2);
                float u = -denu / (num + EPS_F);
                bool ok = (t > 0.f) && (t < 1.f) && (u > 0.f) && (u < 1.f) && (num != 0.f);
                int idx = 8 + ii*4 + jj;
                vx[idx] = ok ? (ex1 + t * (ex2 - ex1)) : 0.f;
                vy[idx] = ok ? (ey1 + t * (ey2 - ey1)) : 0.f;
                vv[idx] = ok;
            }
        }

        // centroid of valid vertices
        float sx = 0.f, sy = 0.f; int nv = 0;
        #pragma unroll
        for (int k = 0; k < 24; ++k) {
            if (vv[k]) { sx += vx[k]; sy += vy[k]; nv++; }
        }
        float dnv = (float)(nv < 1 ? 1 : nv);
        float mx = sx / dnv, my = sy / dnv;

        // pseudo-angle key (strictly monotone in atan2; NaN for invalid)
        float pp[24];
        #pragma unroll
        for (int k = 0; k < 24; ++k) {
            float dx = vx[k] - mx, dy = vy[k] - my;
            vx[k] = dx; vy[k] = dy;
            float ax = fabsf(dx), ay = fabsf(dy);
            float dd = ax + ay;
            float tt = (dd > 0.f) ? (dy / dd) : 0.f;
            float p  = (dx >= 0.f) ? tt
                     : (__builtin_signbitf(dy) ? (-2.f - tt) : (2.f - tt));
            pp[k] = vv[k] ? p : __builtin_nanf("");
        }

        // global min key (wrap target), stable (first index on ties)
        float minp = INFINITY, minx = 0.f, miny = 0.f;
        #pragma unroll
        for (int k = 0; k < 24; ++k) {
            bool upd = pp[k] < minp;          // NaN never updates
            minp = upd ? pp[k] : minp;
            minx = upd ? vx[k] : minx;
            miny = upd ? vy[k] : miny;
        }

        // successor scan: area2 = sum over valid u of (u x succ(u))
        float area2 = 0.f;
        #pragma unroll
        for (int u2 = 0; u2 < 24; ++u2) {
            float pu = pp[u2];
            float bp = INFINITY, bx = minx, by = miny;
            #pragma unroll
            for (int v2 = 0; v2 < 24; ++v2) {
                if (v2 == u2) continue;
                float pv = pp[v2];
                // strictly-after u in stable (angle, index) order
                bool gt  = (v2 > u2) ? (pv >= pu) : (pv > pu);
                bool upd = gt && (pv < bp);   // keeps lexicographic min
                bp = upd ? pv : bp;
                bx = upd ? vx[v2] : bx;
                by = upd ? vy[v2] : by;
            }
            if (vv[u2]) area2 += vx[u2] * by - vy[u2] * bx;
        }
        float inter2d = fabsf(area2) * 0.5f;

        // 3D extension
        float z1 = b1[2], hh1 = b1[5], z2 = b2[2], hh2 = b2[5];
        float zmax = fminf(z1 + hh1 * 0.5f, z2 + hh2 * 0.5f);
        float zmin = fmaxf(z1 - hh1 * 0.5f, z2 - hh2 * 0.5f);
        float inter3d = inter2d * fmaxf(zmax - zmin, 0.f);
        float vol1 = b1[3] * b1[4] * b1[5];
        float vol2 = b2[3] * b2[4] * b2[5];
        float iou = inter3d / (vol1 + vol2 - inter3d);
        float target = iou * 2.f - 1.f;
        wabs = fabsf(pred_iou[i] - target) * m;
    }

    // block reduction: wave shfl-xor, then LDS across 4 waves, then atomic
    #pragma unroll
    for (int off = 32; off > 0; off >>= 1) {
        wabs += __shfl_xor(wabs, off);
        mval += __shfl_xor(mval, off);
    }
    __shared__ float sw[4], sm[4];
    int lane = threadIdx.x & 63;
    int wid  = threadIdx.x >> 6;
    if (lane == 0) { sw[wid] = wabs; sm[wid] = mval; }
    __syncthreads();
    if (threadIdx.x == 0) {
        float tw = sw[0] + sw[1] + sw[2] + sw[3];
        float tm = sm[0] + sm[1] + sm[2] + sm[3];
        atomicAdd(&acc[0], (double)tw);
        atomicAdd(&acc[1], (double)tm);
    }
}

__global__ void __launch_bounds__(64) iou3d_final(const double* __restrict__ acc,
                                                  float* __restrict__ out) {
    if (threadIdx.x == 0 && blockIdx.x == 0) {
        double s = acc[0];
        double dm = acc[1];
        double denom = dm > 1e-4 ? dm : 1e-4;
        out[0] = (float)(s / denom);   // LOSS_WEIGHT = 1
    }
}

extern "C" void kernel_launch(void* const* d_in, const int* in_sizes, int n_in,
                              void* d_out, int out_size, void* d_ws, size_t ws_size,
                              hipStream_t stream) {
    const float* pred_iou   = (const float*)d_in[0];
    const float* pred_boxes = (const float*)d_in[1];
    const float* gt_boxes   = (const float*)d_in[2];
    const int*   mask       = (const int*)d_in[3];
    float* out = (float*)d_out;
    double* acc = (double*)d_ws;

    int N = in_sizes[0];
    int blocks = (N + 255) / 256;

    iou3d_init<<<1, 64, 0, stream>>>(acc);
    iou3d_main<<<blocks, 256, 0, stream>>>(pred_iou, pred_boxes, gt_boxes, mask, acc, N);
    iou3d_final<<<1, 64, 0, stream>>>(acc, out);
}

// Round 3
// 72.136 us; speedup vs baseline: 1.0377x; 1.0377x over previous
//
#include <hip/hip_runtime.h>
#include <math.h>

#define EPS_F 1e-8f

__device__ __forceinline__ float frcp(float x) { return __builtin_amdgcn_rcpf(x); }

__global__ void __launch_bounds__(256) iou3d_init(double* acc) {
    acc[0] = 0.0;
    acc[1] = 0.0;
}

__global__ void __launch_bounds__(256) iou3d_main(
    const float* __restrict__ pred_iou,
    const float* __restrict__ pred_boxes,   // N x 7: x y z w l h yaw
    const float* __restrict__ gt_boxes,     // N x 8: x y z w l h sin cos
    const int*   __restrict__ mask,
    double* __restrict__ acc,
    int N)
{
    int i = blockIdx.x * blockDim.x + threadIdx.x;
    float wabs = 0.f, mval = 0.f;

    if (i < N) {
        const float* b1 = pred_boxes + (size_t)i * 7;
        const float* b2 = gt_boxes   + (size_t)i * 8;
        float m = (float)mask[i];
        mval = m;

        float x1c = b1[0], y1c = b1[1], w1 = b1[3], h1 = b1[4], a1 = b1[6];
        float x2c = b2[0], y2c = b2[1], w2 = b2[3], h2 = b2[4];
        float s2v = b2[6], c2v = b2[7];

        // cos/sin of gt yaw without atan2: cos(atan2(s,c)) = c/sqrt(s^2+c^2)
        float invn = rsqrtf(s2v * s2v + c2v * c2v);
        float cs2 = c2v * invn, sn2 = s2v * invn;
        float sn1, cs1;
        sincosf(a1, &sn1, &cs1);

        const float DX[4] = {0.5f, -0.5f, -0.5f, 0.5f};
        const float DY[4] = {0.5f,  0.5f, -0.5f, -0.5f};
        float c1x[4], c1y[4], c2x[4], c2y[4];
        #pragma unroll
        for (int k = 0; k < 4; ++k) {
            float cx = DX[k] * w1, cy = DY[k] * h1;
            c1x[k] = cx * cs1 - cy * sn1 + x1c;
            c1y[k] = cx * sn1 + cy * cs1 + y1c;
            float gx = DX[k] * w2, gy = DY[k] * h2;
            c2x[k] = gx * cs2 - gy * sn2 + x2c;
            c2y[k] = gx * sn2 + gy * cs2 + y2c;
        }

        float xx[24], yy[24], kk[24];
        bool  vv[24];

        // corner containment tests (reference-exact predicates, rcp for divides)
        {
            float abx = c2x[1] - c2x[0], aby = c2y[1] - c2y[0];
            float adx = c2x[3] - c2x[0], ady = c2y[3] - c2y[0];
            float iab = frcp(abx * abx + aby * aby);
            float iad = frcp(adx * adx + ady * ady);
            #pragma unroll
            for (int k = 0; k < 4; ++k) {
                float amx = c1x[k] - c2x[0], amy = c1y[k] - c2y[0];
                float pab = (abx * amx + aby * amy) * iab;
                float pad = (adx * amx + ady * amy) * iad;
                xx[k] = c1x[k]; yy[k] = c1y[k];
                vv[k] = (pab > -1e-6f) && (pab < 1.f + 1e-6f) &&
                        (pad > -1e-6f) && (pad < 1.f + 1e-6f);
            }
            abx = c1x[1] - c1x[0]; aby = c1y[1] - c1y[0];
            adx = c1x[3] - c1x[0]; ady = c1y[3] - c1y[0];
            iab = frcp(abx * abx + aby * aby);
            iad = frcp(adx * adx + ady * ady);
            #pragma unroll
            for (int k = 0; k < 4; ++k) {
                float amx = c2x[k] - c1x[0], amy = c2y[k] - c1y[0];
                float pab = (abx * amx + aby * amy) * iab;
                float pad = (adx * amx + ady * amy) * iad;
                xx[4 + k] = c2x[k]; yy[4 + k] = c2y[k];
                vv[4 + k] = (pab > -1e-6f) && (pab < 1.f + 1e-6f) &&
                            (pad > -1e-6f) && (pad < 1.f + 1e-6f);
            }
        }

        // 16 edge-pair points — REFERENCE-EXACT formulas (note: reference's t is
        // the NEGATED standard parameter; do NOT "fix" to true segment clipping)
        #pragma unroll
        for (int ii = 0; ii < 4; ++ii) {
            float ex1 = c1x[ii],       ey1 = c1y[ii];
            float ex2 = c1x[(ii+1)&3], ey2 = c1y[(ii+1)&3];
            #pragma unroll
            for (int jj = 0; jj < 4; ++jj) {
                float ex3 = c2x[jj],       ey3 = c2y[jj];
                float ex4 = c2x[(jj+1)&3], ey4 = c2y[(jj+1)&3];
                float num  = (ex2-ex1)*(ey3-ey4) - (ey2-ey1)*(ex3-ex4);
                float dent = (ex1-ex3)*(ey3-ey4) - (ey1-ey3)*(ex3-ex4);
                float denu = (ex1-ex3)*(ey1-ey2) - (ey1-ey3)*(ex1-ex2);
                float rn = frcp(num + EPS_F);
                float t = dent * rn;
                float u = -denu * rn;
                bool ok = (t > 0.f) && (t < 1.f) && (u > 0.f) && (u < 1.f) && (num != 0.f);
                int idx = 8 + ii*4 + jj;
                xx[idx] = ex1 + t * (ex2 - ex1);
                yy[idx] = ey1 + t * (ey2 - ey1);
                vv[idx] = ok;
            }
        }

        // centroid of valid vertices
        float sx = 0.f, sy = 0.f; int nv = 0;
        #pragma unroll
        for (int k = 0; k < 24; ++k) {
            sx += vv[k] ? xx[k] : 0.f;
            sy += vv[k] ? yy[k] : 0.f;
            nv += vv[k] ? 1 : 0;
        }
        float dnv = (float)(nv < 1 ? 1 : nv);
        float mx = sx / dnv, my = sy / dnv;

        // pseudo-angle key: strictly monotone in atan2 (incl. signed-zero edge);
        // +INF for invalid (matches reference's inf, sorts to the end)
        #pragma unroll
        for (int k = 0; k < 24; ++k) {
            float dx = xx[k] - mx, dy = yy[k] - my;
            xx[k] = dx; yy[k] = dy;
            float ax = fabsf(dx), ay = fabsf(dy);
            float dd = ax + ay;
            float tt = (dd > 0.f) ? dy * frcp(dd) : 0.f;
            float p  = (dx >= 0.f) ? tt
                     : (__builtin_signbitf(dy) ? (-2.f - tt) : (2.f - tt));
            kk[k] = vv[k] ? p : INFINITY;
        }

        // Batcher odd-even mergesort: 32-network pruned to slots <24.
        // (+INF padding at 24..31 makes every pruned CE a provable no-op.)
        // All indices are compile-time after unrolling -> stays in VGPRs.
        #pragma unroll
        for (int pb = 1; pb < 32; pb <<= 1) {
          #pragma unroll
          for (int qb = pb; qb >= 1; qb >>= 1) {
            #pragma unroll
            for (int jb = qb % pb; jb + qb < 32; jb += 2 * qb) {
              #pragma unroll
              for (int ib = 0; ib < qb; ++ib) {
                int a = jb + ib, b = jb + ib + qb;
                if (b < 24 && (a / (2 * pb)) == (b / (2 * pb))) {
                    bool sw = kk[b] < kk[a];
                    float tk = kk[a], tx = xx[a], ty = yy[a];
                    kk[a] = sw ? kk[b] : tk;  xx[a] = sw ? xx[b] : tx;  yy[a] = sw ? yy[b] : ty;
                    kk[b] = sw ? tk : kk[b];  xx[b] = sw ? tx : xx[b];  yy[b] = sw ? ty : yy[b];
                }
              }
            }
          }
        }

        // shoelace over sorted valid vertices, positions >= nv padded with first
        // (exactly the reference's pos_valid trick: 23 consecutive cross terms)
        float s0x = xx[0], s0y = yy[0];
        float area2 = 0.f;
        #pragma unroll
        for (int k = 0; k < 23; ++k) {
            float ax2 = (k < nv)     ? xx[k]   : s0x;
            float ay2 = (k < nv)     ? yy[k]   : s0y;
            float bx2 = (k + 1 < nv) ? xx[k+1] : s0x;
            float by2 = (k + 1 < nv) ? yy[k+1] : s0y;
            area2 += ax2 * by2 - ay2 * bx2;
        }
        float inter2d = fabsf(area2) * 0.5f;

        // 3D extension
        float z1 = b1[2], d1 = b1[5], z2 = b2[2], d2 = b2[5];
        float zmax = fminf(z1 + d1 * 0.5f, z2 + d2 * 0.5f);
        float zmin = fmaxf(z1 - d1 * 0.5f, z2 - d2 * 0.5f);
        float inter3d = inter2d * fmaxf(zmax - zmin, 0.f);
        float vol1 = w1 * h1 * d1;
        float vol2 = w2 * h2 * d2;
        float iou = inter3d / (vol1 + vol2 - inter3d);
        float target = iou * 2.f - 1.f;
        wabs = fabsf(pred_iou[i] - target) * m;
    }

    // block reduction: wave shfl-xor, then LDS across 4 waves, then atomic
    #pragma unroll
    for (int off = 32; off > 0; off >>= 1) {
        wabs += __shfl_xor(wabs, off);
        mval += __shfl_xor(mval, off);
    }
    __shared__ float sw_[4], sm_[4];
    int lane = threadIdx.x & 63;
    int wid  = threadIdx.x >> 6;
    if (lane == 0) { sw_[wid] = wabs; sm_[wid] = mval; }
    __syncthreads();
    if (threadIdx.x == 0) {
        float tw = sw_[0] + sw_[1] + sw_[2] + sw_[3];
        float tm = sm_[0] + sm_[1] + sm_[2] + sm_[3];
        atomicAdd(&acc[0], (double)tw);
        atomicAdd(&acc[1], (double)tm);
    }
}

__global__ void __launch_bounds__(64) iou3d_final(const double* __restrict__ acc,
                                                  float* __restrict__ out) {
    if (threadIdx.x == 0 && blockIdx.x == 0) {
        double s  = acc[0];
        double dm = acc[1];
        double denom = dm > 1e-4 ? dm : 1e-4;
        out[0] = (float)(s / denom);   // LOSS_WEIGHT = 1
    }
}

extern "C" void kernel_launch(void* const* d_in, const int* in_sizes, int n_in,
                              void* d_out, int out_size, void* d_ws, size_t ws_size,
                              hipStream_t stream) {
    const float* pred_iou   = (const float*)d_in[0];
    const float* pred_boxes = (const float*)d_in[1];
    const float* gt_boxes   = (const float*)d_in[2];
    const int*   mask       = (const int*)d_in[3];
    float* out = (float*)d_out;
    double* acc = (double*)d_ws;

    int N = in_sizes[0];
    int blocks = (N + 255) / 256;

    iou3d_init<<<1, 64, 0, stream>>>(acc);
    iou3d_main<<<blocks, 256, 0, stream>>>(pred_iou, pred_boxes, gt_boxes, mask, acc, N);
    iou3d_final<<<1, 64, 0, stream>>>(acc, out);
}

// Round 4
// 64.154 us; speedup vs baseline: 1.1668x; 1.1244x over previous
//
#include <hip/hip_runtime.h>
#include <math.h>

#define EPS_F 1e-8f

__device__ __forceinline__ float frcp(float x) { return __builtin_amdgcn_rcpf(x); }

__global__ void __launch_bounds__(256) iou3d_init(double* acc) {
    acc[0] = 0.0;
    acc[1] = 0.0;
}

__global__ void __launch_bounds__(256) iou3d_main(
    const float* __restrict__ pred_iou,
    const float* __restrict__ pred_boxes,   // N x 7: x y z w l h yaw
    const float* __restrict__ gt_boxes,     // N x 8: x y z w l h sin cos
    const int*   __restrict__ mask,
    double* __restrict__ acc,
    int N)
{
    // per-thread vertex scratch: 24 slots x (x,y), stride 50 dwords (200 B,
    // 8B-aligned for b64, 50 mod 32 = 18 spreads banks acceptably)
    __shared__ float vbuf[256 * 50];
    const int dbase = threadIdx.x * 50;

    int i = blockIdx.x * blockDim.x + threadIdx.x;
    float wabs = 0.f, mval = 0.f;

    if (i < N) {
        const float* b1 = pred_boxes + (size_t)i * 7;
        const float* b2 = gt_boxes   + (size_t)i * 8;
        float m = (float)mask[i];
        mval = m;

        float x1c = b1[0], y1c = b1[1], w1 = b1[3], h1 = b1[4], a1 = b1[6];
        float x2c = b2[0], y2c = b2[1], w2 = b2[3], h2 = b2[4];
        float s2v = b2[6], c2v = b2[7];

        // cos/sin of gt yaw without atan2: cos(atan2(s,c)) = c/sqrt(s^2+c^2)
        float invn = rsqrtf(s2v * s2v + c2v * c2v);
        float cs2 = c2v * invn, sn2 = s2v * invn;
        // pred yaw in [-pi,pi]: raw v_sin/v_cos (input in revolutions)
        const float INV2PI = 0.15915494309189535f;
        float sn1 = __builtin_amdgcn_sinf(a1 * INV2PI);
        float cs1 = __builtin_amdgcn_cosf(a1 * INV2PI);

        const float DX[4] = {0.5f, -0.5f, -0.5f, 0.5f};
        const float DY[4] = {0.5f,  0.5f, -0.5f, -0.5f};
        float c1x[4], c1y[4], c2x[4], c2y[4];
        #pragma unroll
        for (int k = 0; k < 4; ++k) {
            float cx = DX[k] * w1, cy = DY[k] * h1;
            c1x[k] = cx * cs1 - cy * sn1 + x1c;
            c1y[k] = cx * sn1 + cy * cs1 + y1c;
            float gx = DX[k] * w2, gy = DY[k] * h2;
            c2x[k] = gx * cs2 - gy * sn2 + x2c;
            c2y[k] = gx * sn2 + gy * cs2 + y2c;
        }

        unsigned vmask = 0;          // bit k = vertex k valid
        float sx = 0.f, sy = 0.f;    // sums of VALID vertices

        // corner containment (reference-exact predicates), slots 0..7
        {
            float abx = c2x[1] - c2x[0], aby = c2y[1] - c2y[0];
            float adx = c2x[3] - c2x[0], ady = c2y[3] - c2y[0];
            float iab = frcp(abx * abx + aby * aby);
            float iad = frcp(adx * adx + ady * ady);
            #pragma unroll
            for (int k = 0; k < 4; ++k) {
                float amx = c1x[k] - c2x[0], amy = c1y[k] - c2y[0];
                float pab = (abx * amx + aby * amy) * iab;
                float pad = (adx * amx + ady * amy) * iad;
                bool ok = (pab > -1e-6f) && (pab < 1.f + 1e-6f) &&
                          (pad > -1e-6f) && (pad < 1.f + 1e-6f);
                vbuf[dbase + 2*k]     = c1x[k];
                vbuf[dbase + 2*k + 1] = c1y[k];
                vmask |= ok ? (1u << k) : 0u;
                sx += ok ? c1x[k] : 0.f;
                sy += ok ? c1y[k] : 0.f;
            }
            abx = c1x[1] - c1x[0]; aby = c1y[1] - c1y[0];
            adx = c1x[3] - c1x[0]; ady = c1y[3] - c1y[0];
            iab = frcp(abx * abx + aby * aby);
            iad = frcp(adx * adx + ady * ady);
            #pragma unroll
            for (int k = 0; k < 4; ++k) {
                float amx = c2x[k] - c1x[0], amy = c2y[k] - c1y[0];
                float pab = (abx * amx + aby * amy) * iab;
                float pad = (adx * amx + ady * amy) * iad;
                bool ok = (pab > -1e-6f) && (pab < 1.f + 1e-6f) &&
                          (pad > -1e-6f) && (pad < 1.f + 1e-6f);
                vbuf[dbase + 2*(4+k)]     = c2x[k];
                vbuf[dbase + 2*(4+k) + 1] = c2y[k];
                vmask |= ok ? (1u << (4 + k)) : 0u;
                sx += ok ? c2x[k] : 0.f;
                sy += ok ? c2y[k] : 0.f;
            }
        }

        // 16 edge-pair points, slots 8..23 — REFERENCE-EXACT formulas
        // (reference's t is the NEGATED standard parameter; replicate, not fix)
        #pragma unroll
        for (int ii = 0; ii < 4; ++ii) {
            float ex1 = c1x[ii],       ey1 = c1y[ii];
            float ex2 = c1x[(ii+1)&3], ey2 = c1y[(ii+1)&3];
            #pragma unroll
            for (int jj = 0; jj < 4; ++jj) {
                float ex3 = c2x[jj],       ey3 = c2y[jj];
                float ex4 = c2x[(jj+1)&3], ey4 = c2y[(jj+1)&3];
                float num  = (ex2-ex1)*(ey3-ey4) - (ey2-ey1)*(ex3-ex4);
                float dent = (ex1-ex3)*(ey3-ey4) - (ey1-ey3)*(ex3-ex4);
                float denu = (ex1-ex3)*(ey1-ey2) - (ey1-ey3)*(ex1-ex2);
                float rn = frcp(num + EPS_F);
                float t = dent * rn;
                float u = -denu * rn;
                bool ok = (t > 0.f) && (t < 1.f) && (u > 0.f) && (u < 1.f) && (num != 0.f);
                int idx = 8 + ii*4 + jj;
                float px_ = ex1 + t * (ex2 - ex1);
                float py_ = ey1 + t * (ey2 - ey1);
                vbuf[dbase + 2*idx]     = px_;
                vbuf[dbase + 2*idx + 1] = py_;
                vmask |= ok ? (1u << idx) : 0u;
                sx += ok ? px_ : 0.f;
                sy += ok ? py_ : 0.f;
            }
        }

        int nv = __popc(vmask);
        float rdn = frcp((float)(nv < 1 ? 1 : nv));
        float mx = sx * rdn, my = sy * rdn;

        // angle pass: pseudo-angle (monotone in atan2) -> sortable u32,
        // low 5 bits = index (stable tiebreak, matches stable argsort)
        unsigned kk[24];
        #pragma unroll
        for (int k = 0; k < 24; ++k) {
            float dx = vbuf[dbase + 2*k]     - mx;
            float dy = vbuf[dbase + 2*k + 1] - my;
            float ax = fabsf(dx), ay = fabsf(dy);
            float dd = ax + ay;
            float tt = (dd > 0.f) ? dy * frcp(dd) : 0.f;
            float p  = (dx >= 0.f) ? tt
                     : (__builtin_signbitf(dy) ? (-2.f - tt) : (2.f - tt));
            int sb = __float_as_int(p);
            unsigned u = (unsigned)sb ^ (unsigned)((sb >> 31) | 0x80000000);
            bool v = (vmask >> k) & 1u;
            kk[k] = v ? ((u & 0xFFFFFFE0u) | (unsigned)k)
                      : (0xFFFFFFE0u | (unsigned)k);   // +inf region, idx order
        }

        // Batcher odd-even mergesort (32-net pruned to <24; validated round 3),
        // now 1-wide u32 payload: CE = v_min_u32 + v_max_u32
        #pragma unroll
        for (int pb = 1; pb < 32; pb <<= 1) {
          #pragma unroll
          for (int qb = pb; qb >= 1; qb >>= 1) {
            #pragma unroll
            for (int jb = qb % pb; jb + qb < 32; jb += 2 * qb) {
              #pragma unroll
              for (int ib = 0; ib < qb; ++ib) {
                int a = jb + ib, b = jb + ib + qb;
                if (b < 24 && (a / (2 * pb)) == (b / (2 * pb))) {
                    unsigned ka = kk[a], kb2 = kk[b];
                    kk[a] = ka < kb2 ? ka : kb2;
                    kk[b] = ka < kb2 ? kb2 : ka;
                }
              }
            }
          }
        }

        // shoelace in centroid-relative coords, gather by sorted index,
        // positions >= nv padded with first sorted vertex (reference-exact)
        float area2 = 0.f, fx = 0.f, fy = 0.f, px = 0.f, py = 0.f;
        #pragma unroll
        for (int k = 0; k < 24; ++k) {
            unsigned o = kk[k] & 31u;
            float x = vbuf[dbase + 2*o]     - mx;
            float y = vbuf[dbase + 2*o + 1] - my;
            if (k == 0) { fx = x; fy = y; px = x; py = y; }
            else {
                bool use = (k < nv);
                float cx_ = use ? x : fx;
                float cy_ = use ? y : fy;
                area2 += px * cy_ - py * cx_;
                px = cx_; py = cy_;
            }
        }
        float inter2d = fabsf(area2) * 0.5f;

        // 3D extension
        float z1 = b1[2], d1 = b1[5], z2 = b2[2], d2 = b2[5];
        float zmax = fminf(z1 + d1 * 0.5f, z2 + d2 * 0.5f);
        float zmin = fmaxf(z1 - d1 * 0.5f, z2 - d2 * 0.5f);
        float inter3d = inter2d * fmaxf(zmax - zmin, 0.f);
        float vol1 = w1 * h1 * d1;
        float vol2 = w2 * h2 * d2;
        float iou = inter3d / (vol1 + vol2 - inter3d);
        float target = iou * 2.f - 1.f;
        wabs = fabsf(pred_iou[i] - target) * m;
    }

    // block reduction: wave shfl-xor, then LDS across 4 waves, then atomic
    #pragma unroll
    for (int off = 32; off > 0; off >>= 1) {
        wabs += __shfl_xor(wabs, off);
        mval += __shfl_xor(mval, off);
    }
    __shared__ float sw_[4], sm_[4];
    int lane = threadIdx.x & 63;
    int wid  = threadIdx.x >> 6;
    if (lane == 0) { sw_[wid] = wabs; sm_[wid] = mval; }
    __syncthreads();
    if (threadIdx.x == 0) {
        float tw = sw_[0] + sw_[1] + sw_[2] + sw_[3];
        float tm = sm_[0] + sm_[1] + sm_[2] + sm_[3];
        atomicAdd(&acc[0], (double)tw);
        atomicAdd(&acc[1], (double)tm);
    }
}

__global__ void __launch_bounds__(64) iou3d_final(const double* __restrict__ acc,
                                                  float* __restrict__ out) {
    if (threadIdx.x == 0 && blockIdx.x == 0) {
        double s  = acc[0];
        double dm = acc[1];
        double denom = dm > 1e-4 ? dm : 1e-4;
        out[0] = (float)(s / denom);   // LOSS_WEIGHT = 1
    }
}

extern "C" void kernel_launch(void* const* d_in, const int* in_sizes, int n_in,
                              void* d_out, int out_size, void* d_ws, size_t ws_size,
                              hipStream_t stream) {
    const float* pred_iou   = (const float*)d_in[0];
    const float* pred_boxes = (const float*)d_in[1];
    const float* gt_boxes   = (const float*)d_in[2];
    const int*   mask       = (const int*)d_in[3];
    float* out = (float*)d_out;
    double* acc = (double*)d_ws;

    int N = in_sizes[0];
    int blocks = (N + 255) / 256;

    iou3d_init<<<1, 64, 0, stream>>>(acc);
    iou3d_main<<<blocks, 256, 0, stream>>>(pred_iou, pred_boxes, gt_boxes, mask, acc, N);
    iou3d_final<<<1, 64, 0, stream>>>(acc, out);
}